// Round 11
// baseline (214.928 us; speedup 1.0000x reference)
//
#include <hip/hip_runtime.h>
#include <hip/hip_bf16.h>
#include <math.h>

#define T0 128
#define BN 256           // B*N = 8*32
#define Ff 128
#define Hh 256
#define NODE0 32768      // BN*T0
#define E0 262144        // NODE0*8
#define T1 64
#define NODE1 16384      // BN*T1
#define E1 131072
#define CAP 48           // per-node in-edge capacity; deg ~ Poisson(8), P(>48) ~ 1e-25

typedef __attribute__((ext_vector_type(8))) short bhalf8;
typedef __attribute__((ext_vector_type(4))) float floatx4;
typedef __attribute__((ext_vector_type(16))) float floatx16;

__device__ __forceinline__ unsigned short f2bf(float x) {
  union { float f; unsigned u; } v; v.f = x;
  unsigned r = v.u + 0x7fff + ((v.u >> 16) & 1);
  return (unsigned short)(r >> 16);
}
__device__ __forceinline__ float bf2f(unsigned short b) {
  union { unsigned u; float f; } v; v.u = ((unsigned)b) << 16;
  return v.f;
}

// ---------------- fused prep + edge-fill kernel ----------------
// [0,128): W0 -> Wbot0/Wd0 ; [128,384): W1 -> Wbot1/Wd1
// [384,1664): Wc0 -> Wtb0 ; [1664,2944): Wc1 -> Wtb1
// [2944,4480): bucketed edge fill for both layers
__global__ void k_prepfill(const float* __restrict__ W0, unsigned short* __restrict__ Wbot0,
                           unsigned short* __restrict__ Wd0,
                           const float* __restrict__ W1, unsigned short* __restrict__ Wbot1,
                           unsigned short* __restrict__ Wd1,
                           const float* __restrict__ Wc0, unsigned short* __restrict__ Wtb0,
                           const float* __restrict__ Wc1, unsigned short* __restrict__ Wtb1,
                           const int* __restrict__ ei0, const int* __restrict__ ei1,
                           int* __restrict__ cnt0, int* __restrict__ cnt1,
                           int* __restrict__ slot0, int* __restrict__ slot1) {
  int b = blockIdx.x;
  int tid = threadIdx.x;
  if (b < 128) {
    int idx = b * 256 + tid;          // 32768 = 256*128
    int n = idx >> 7, k = idx & 127;
    float top = W0[(size_t)k * 256 + n];
    float bot = W0[(size_t)(128 + k) * 256 + n];
    Wbot0[idx] = f2bf(bot);
    Wd0[idx]   = f2bf(top - bot);
  } else if (b < 384) {
    int idx = (b - 128) * 256 + tid;  // 65536 = 256*256
    int n = idx >> 8, k = idx & 255;
    float top = W1[(size_t)k * 256 + n];
    float bot = W1[(size_t)(256 + k) * 256 + n];
    Wbot1[idx] = f2bf(bot);
    Wd1[idx]   = f2bf(top - bot);
  } else if (b < 1664) {
    int idx = (b - 384) * 256 + tid;  // 5*65536
    int tap = idx >> 16, o = (idx >> 8) & 255, i = idx & 255;
    Wtb0[idx] = f2bf(Wc0[((size_t)o * 256 + i) * 5 + tap]);
  } else if (b < 2944) {
    int idx = (b - 1664) * 256 + tid;
    int tap = idx >> 16, o = (idx >> 8) & 255, i = idx & 255;
    Wtb1[idx] = f2bf(Wc1[((size_t)o * 256 + i) * 5 + tap]);
  } else {
    int e = (b - 2944) * 256 + tid;   // E0+E1 = 393216 over 1536 blocks
    if (e < E0) {
      int d = ei0[E0 + e];
      int p = atomicAdd(&cnt0[d], 1);
      if (p < CAP) slot0[(size_t)d * CAP + p] = ei0[e];
    } else {
      int e2 = e - E0;
      int d = ei1[E1 + e2];
      int p = atomicAdd(&cnt1[d], 1);
      if (p < CAP) slot1[(size_t)d * CAP + p] = ei1[e2];
    }
  }
}

// ---------------- fused dual-output MFMA GEMM ----------------
// One block: 64 rows x 128 cols, computing BOTH Bm = A@Wbot (bf16)
// and P = A@Wd + bias (bf16). A staged once per kb; Wbot/Wd in two LDS buffers.
// F32A: A is the fp32 `data` tensor [T][BN][F]; row bn*T0+t is gathered and
// converted to bf16 during staging (identical rounding to the old permute).
template <bool F32A>
__global__ __launch_bounds__(256) void k_gemm2(const float* __restrict__ Af,
                                               const unsigned short* __restrict__ Ab,
                                               const unsigned short* __restrict__ Wbot,
                                               const unsigned short* __restrict__ Wd,
                                               unsigned short* __restrict__ Bm,
                                               unsigned short* __restrict__ P, int K,
                                               const float* __restrict__ bias) {
  __shared__ __align__(16) short A_lds[64 * 72];
  __shared__ __align__(16) short B0_lds[128 * 72];
  __shared__ __align__(16) short B1_lds[128 * 72];
  int tid = threadIdx.x;
  int row0 = blockIdx.x * 64;
  int col0 = blockIdx.y * 128;
  int lane = tid & 63, wv = tid >> 6;
  int m16 = lane & 15, quad = lane >> 4;
  int sr = tid >> 3, sseg = tid & 7;

  floatx4 accB[8], accP[8];
#pragma unroll
  for (int nt = 0; nt < 8; ++nt) {
    accB[nt] = (floatx4){0.f, 0.f, 0.f, 0.f};
    accP[nt] = (floatx4){0.f, 0.f, 0.f, 0.f};
  }

  for (int kb = 0; kb < K; kb += 64) {
    __syncthreads();
#pragma unroll
    for (int i = 0; i < 2; ++i) {
      int r = sr + i * 32;
      if (F32A) {
        int rg = row0 + r;
        int t = rg & (T0 - 1), bn = rg >> 7;
        const float* s = Af + ((size_t)t * BN + bn) * Ff + kb + sseg * 8;
        float4 f0 = *(const float4*)s;
        float4 f1 = *(const float4*)(s + 4);
        unsigned short o[8];
        o[0] = f2bf(f0.x); o[1] = f2bf(f0.y); o[2] = f2bf(f0.z); o[3] = f2bf(f0.w);
        o[4] = f2bf(f1.x); o[5] = f2bf(f1.y); o[6] = f2bf(f1.z); o[7] = f2bf(f1.w);
        *(int4*)&A_lds[r * 72 + sseg * 8] = *(int4*)o;
      } else {
        *(int4*)&A_lds[r * 72 + sseg * 8] =
            *(const int4*)(Ab + (size_t)(row0 + r) * K + kb + sseg * 8);
      }
    }
#pragma unroll
    for (int i = 0; i < 4; ++i) {
      int r = sr + i * 32;
      *(int4*)&B0_lds[r * 72 + sseg * 8] =
          *(const int4*)(Wbot + (size_t)(col0 + r) * K + kb + sseg * 8);
      *(int4*)&B1_lds[r * 72 + sseg * 8] =
          *(const int4*)(Wd + (size_t)(col0 + r) * K + kb + sseg * 8);
    }
    __syncthreads();
#pragma unroll
    for (int ks = 0; ks < 2; ++ks) {
      bhalf8 a = *(const bhalf8*)&A_lds[(wv * 16 + m16) * 72 + ks * 32 + quad * 8];
#pragma unroll
      for (int nt = 0; nt < 8; ++nt) {
        bhalf8 b0 = *(const bhalf8*)&B0_lds[(nt * 16 + m16) * 72 + ks * 32 + quad * 8];
        accB[nt] = __builtin_amdgcn_mfma_f32_16x16x32_bf16(a, b0, accB[nt], 0, 0, 0);
        bhalf8 b1 = *(const bhalf8*)&B1_lds[(nt * 16 + m16) * 72 + ks * 32 + quad * 8];
        accP[nt] = __builtin_amdgcn_mfma_f32_16x16x32_bf16(a, b1, accP[nt], 0, 0, 0);
      }
    }
  }

  int g0 = row0 + wv * 16 + quad * 4;
#pragma unroll
  for (int nt = 0; nt < 8; ++nt) {
    int c = col0 + nt * 16 + m16;
    float bv = bias[c];
#pragma unroll
    for (int r = 0; r < 4; ++r) {
      Bm[(size_t)(g0 + r) * 256 + c] = f2bf(accB[nt][r]);
      P[(size_t)(g0 + r) * 256 + c]  = f2bf(accP[nt][r] + bv);
    }
  }
}

// ---------------- segment max + fused relu epilogue ----------------
// per node: M = max over in-edge sources of Bm rows (-inf if empty),
// X1 = relu(P + M)  (empty -> relu(-inf) = 0, matching PyG fill).
// Gather issues 8 concurrent predicated row loads per pass (index clamped to
// n-1; duplicate maxes are idempotent) to keep 8 LLC fetches in flight.
__global__ __launch_bounds__(256) void k_maxg2(const unsigned short* __restrict__ Bm,
                                               const int* __restrict__ cnt,
                                               const int* __restrict__ slot,
                                               const unsigned short* __restrict__ P,
                                               unsigned short* __restrict__ X1) {
  int node = blockIdx.x * 4 + (threadIdx.x >> 6);
  int lane = threadIdx.x & 63;
  int n = cnt[node];
  if (n > CAP) n = CAP;
  const int* sl = slot + (size_t)node * CAP;
  float4 m = make_float4(-INFINITY, -INFINITY, -INFINITY, -INFINITY);
  for (int i = 0; i < n; i += 8) {
    int s[8];
#pragma unroll
    for (int j = 0; j < 8; ++j) {
      int idx = i + j;
      s[j] = sl[(idx < n) ? idx : (n - 1)];
    }
    ushort4 v[8];
#pragma unroll
    for (int j = 0; j < 8; ++j)
      v[j] = *(const ushort4*)(Bm + (size_t)s[j] * 256 + lane * 4);
#pragma unroll
    for (int j = 0; j < 8; ++j) {
      m.x = fmaxf(m.x, bf2f(v[j].x));
      m.y = fmaxf(m.y, bf2f(v[j].y));
      m.z = fmaxf(m.z, bf2f(v[j].z));
      m.w = fmaxf(m.w, bf2f(v[j].w));
    }
  }
  ushort4 p = *(const ushort4*)(P + (size_t)node * 256 + lane * 4);
  ushort4 o;
  o.x = f2bf(fmaxf(bf2f(p.x) + m.x, 0.f));
  o.y = f2bf(fmaxf(bf2f(p.y) + m.y, 0.f));
  o.z = f2bf(fmaxf(bf2f(p.z) + m.z, 0.f));
  o.w = f2bf(fmaxf(bf2f(p.w) + m.w, 0.f));
  *(ushort4*)(X1 + (size_t)node * 256 + lane * 4) = o;
}

// ---------------- MFMA temporal conv: 32x32x16, 256-row x 64-col blocks ----------------
// Y = maxpool2(relu(conv1d(X, Wtb, k=5, pad=2) + bc)); X bf16 [M][256] as [BN][TRows][256]
// 4 waves; wave w owns rows [row0+w*64, +64) with its OWN 68-row halo window, and all
// 64 cols as 2x2 tiles of 32 (rt=2, ct=2 -> 1.0 ds_read per MFMA). Per K-chunk of 32:
// stage 4 halo windows + all 5 taps of B; 40 MFMAs/wave between barrier pairs.
// Halving row-block count (vs 128-row) halves Wtb L2 re-read traffic.
// C/D layout (32x32): col=lane&31, row=(reg&3)+8*(reg>>2)+4*(lane>>5); pool pairs are
// adjacent regs in the same lane.
template <int TRows, bool OUT_F32>
__global__ __launch_bounds__(256) void k_conv32(const unsigned short* __restrict__ X,
                                                const unsigned short* __restrict__ Wtb,
                                                const float* __restrict__ bc,
                                                void* __restrict__ Yout) {
  __shared__ __align__(16) short A_lds[4 * 68 * 40];   // [win][row 0..67][k32 + pad8]
  __shared__ __align__(16) short B_lds[5 * 64 * 40];   // [tap*64 + col][k32 + pad8]
  int tid = threadIdx.x;
  int row0 = blockIdx.x * 256;
  int col0 = blockIdx.y * 64;
  int lane = tid & 63, wv = tid >> 6;
  int l31 = lane & 31, khalf = lane >> 5;

  floatx16 acc[2][2];
#pragma unroll
  for (int rt = 0; rt < 2; ++rt)
#pragma unroll
    for (int ct = 0; ct < 2; ++ct)
#pragma unroll
      for (int r = 0; r < 16; ++r) acc[rt][ct][r] = 0.f;

  for (int kb = 0; kb < 256; kb += 32) {
    __syncthreads();
    // stage A: four 68-row halo windows (rows base-2 .. base+66), zero outside bn
    for (int u = tid; u < 1088; u += 256) {
      int win = u / 272;
      int v = u - win * 272;
      int rr = v >> 2, seg = v & 3;
      int base = row0 + win * 64;
      int lo = base & ~(TRows - 1);
      int gr = base + rr - 2;
      int4 val = {0, 0, 0, 0};
      if (gr >= lo && gr < lo + TRows)
        val = *(const int4*)(X + (size_t)gr * 256 + kb + seg * 8);
      *(int4*)&A_lds[(win * 68 + rr) * 40 + seg * 8] = val;
    }
    // stage B: 5 taps x 64 cols x 32 k
#pragma unroll
    for (int i = 0; i < 5; ++i) {
      int u = tid + i * 256;            // 320 rows x 4 segs
      int r = u >> 2, seg = u & 3;      // r = tap*64 + col
      int tap = r >> 6, col = r & 63;
      *(int4*)&B_lds[r * 40 + seg * 8] =
          *(const int4*)(Wtb + (size_t)tap * 65536 + (size_t)(col0 + col) * 256 + kb + seg * 8);
    }
    __syncthreads();
#pragma unroll
    for (int tap = 0; tap < 5; ++tap) {
#pragma unroll
      for (int ks = 0; ks < 2; ++ks) {
        int ko = ks * 16 + khalf * 8;
        bhalf8 a0 = *(const bhalf8*)&A_lds[(wv * 68 + l31 + tap) * 40 + ko];
        bhalf8 a1 = *(const bhalf8*)&A_lds[(wv * 68 + 32 + l31 + tap) * 40 + ko];
        bhalf8 b0 = *(const bhalf8*)&B_lds[((tap << 6) + l31) * 40 + ko];
        bhalf8 b1 = *(const bhalf8*)&B_lds[((tap << 6) + 32 + l31) * 40 + ko];
        acc[0][0] = __builtin_amdgcn_mfma_f32_32x32x16_bf16(a0, b0, acc[0][0], 0, 0, 0);
        acc[0][1] = __builtin_amdgcn_mfma_f32_32x32x16_bf16(a0, b1, acc[0][1], 0, 0, 0);
        acc[1][0] = __builtin_amdgcn_mfma_f32_32x32x16_bf16(a1, b0, acc[1][0], 0, 0, 0);
        acc[1][1] = __builtin_amdgcn_mfma_f32_32x32x16_bf16(a1, b1, acc[1][1], 0, 0, 0);
      }
    }
  }

#pragma unroll
  for (int rt = 0; rt < 2; ++rt) {
#pragma unroll
    for (int ct = 0; ct < 2; ++ct) {
      int c = col0 + ct * 32 + l31;
      float bv = bc[c];
#pragma unroll
      for (int r = 0; r < 16; r += 2) {
        int rowg = row0 + wv * 64 + rt * 32 + 4 * khalf + 8 * (r >> 2) + (r & 3);
        float y0 = fmaxf(acc[rt][ct][r] + bv, 0.f);
        float y1 = fmaxf(acc[rt][ct][r + 1] + bv, 0.f);
        float p = fmaxf(y0, y1);
        int o = rowg >> 1;
        if (OUT_F32) ((float*)Yout)[(size_t)o * 256 + c] = p;
        else ((unsigned short*)Yout)[(size_t)o * 256 + c] = f2bf(p);
      }
    }
  }
}

extern "C" void kernel_launch(void* const* d_in, const int* in_sizes, int n_in,
                              void* d_out, int out_size, void* d_ws, size_t ws_size,
                              hipStream_t stream) {
  const float* data = (const float*)d_in[0];
  const int* ei0 = (const int*)d_in[2];
  const int* ei1 = (const int*)d_in[3];
  const float* W0  = (const float*)d_in[4];
  const float* b0  = (const float*)d_in[5];
  const float* Wc0 = (const float*)d_in[6];
  const float* bc0 = (const float*)d_in[7];
  const float* W1  = (const float*)d_in[8];
  const float* b1  = (const float*)d_in[9];
  const float* Wc1 = (const float*)d_in[10];
  const float* bc1 = (const float*)d_in[11];
  float* out = (float*)d_out;

  char* base = (char*)d_ws;
  size_t off = 0;
  auto alloc = [&](size_t bytes) { void* p = base + off; off += (bytes + 255) & ~(size_t)255; return p; };
  unsigned short* Bm    = (unsigned short*)alloc((size_t)NODE0 * Hh * 2);
  unsigned short* P     = (unsigned short*)alloc((size_t)NODE0 * Hh * 2);
  unsigned short* X1b   = (unsigned short*)alloc((size_t)NODE0 * Hh * 2);
  unsigned short* Y0b   = (unsigned short*)alloc((size_t)NODE1 * Hh * 2);
  unsigned short* Wbot0 = (unsigned short*)alloc(256 * 128 * 2);
  unsigned short* Wd0   = (unsigned short*)alloc(256 * 128 * 2);
  unsigned short* Wbot1 = (unsigned short*)alloc(256 * 256 * 2);
  unsigned short* Wd1   = (unsigned short*)alloc(256 * 256 * 2);
  unsigned short* Wtb0  = (unsigned short*)alloc(5 * 65536 * 2);
  unsigned short* Wtb1  = (unsigned short*)alloc(5 * 65536 * 2);
  int* cnt0  = (int*)alloc(NODE0 * 4);      // cnt0+cnt1 adjacent: one memset
  int* cnt1  = (int*)alloc(NODE1 * 4);
  int* slot0 = (int*)alloc((size_t)NODE0 * CAP * 4);
  int* slot1 = (int*)alloc((size_t)NODE1 * CAP * 4);

  hipMemsetAsync(cnt0, 0, (NODE0 + NODE1) * sizeof(int), stream);

  k_prepfill<<<4480, 256, 0, stream>>>(W0, Wbot0, Wd0, W1, Wbot1, Wd1,
                                       Wc0, Wtb0, Wc1, Wtb1,
                                       ei0, ei1, cnt0, cnt1, slot0, slot1);

  // ---- layer 0 ----
  k_gemm2<true><<<dim3(NODE0 / 64, 2), 256, 0, stream>>>(data, nullptr, Wbot0, Wd0, Bm, P, 128, b0);
  k_maxg2<<<NODE0 / 4, 256, 0, stream>>>(Bm, cnt0, slot0, P, X1b);
  k_conv32<128, false><<<dim3(NODE0 / 256, 4), 256, 0, stream>>>(X1b, Wtb0, bc0, Y0b);

  // ---- layer 1 ----
  k_gemm2<false><<<dim3(NODE1 / 64, 2), 256, 0, stream>>>(nullptr, Y0b, Wbot1, Wd1, Bm, P, 256, b1);
  k_maxg2<<<NODE1 / 4, 256, 0, stream>>>(Bm, cnt1, slot1, P, X1b);
  k_conv32<64, true><<<dim3(NODE1 / 256, 4), 256, 0, stream>>>(X1b, Wtb1, bc1, out);
}

// Round 12
// 214.101 us; speedup vs baseline: 1.0039x; 1.0039x over previous
//
#include <hip/hip_runtime.h>
#include <hip/hip_bf16.h>
#include <math.h>

#define T0 128
#define BN 256           // B*N = 8*32
#define Ff 128
#define Hh 256
#define NODE0 32768      // BN*T0
#define E0 262144        // NODE0*8
#define T1 64
#define NODE1 16384      // BN*T1
#define E1 131072
#define CAP 48           // per-node in-edge capacity; deg ~ Poisson(8), P(>48) ~ 1e-25

typedef __attribute__((ext_vector_type(8))) short bhalf8;
typedef __attribute__((ext_vector_type(4))) float floatx4;
typedef __attribute__((ext_vector_type(16))) float floatx16;

__device__ __forceinline__ unsigned short f2bf(float x) {
  union { float f; unsigned u; } v; v.f = x;
  unsigned r = v.u + 0x7fff + ((v.u >> 16) & 1);
  return (unsigned short)(r >> 16);
}
__device__ __forceinline__ float bf2f(unsigned short b) {
  union { unsigned u; float f; } v; v.u = ((unsigned)b) << 16;
  return v.f;
}

// ---------------- fused prep + edge-fill kernel ----------------
// [0,128): W0 -> Wbot0/Wd0 ; [128,384): W1 -> Wbot1/Wd1
// [384,1664): Wc0 -> Wtb0 ; [1664,2944): Wc1 -> Wtb1
// [2944,4480): bucketed edge fill for both layers
__global__ void k_prepfill(const float* __restrict__ W0, unsigned short* __restrict__ Wbot0,
                           unsigned short* __restrict__ Wd0,
                           const float* __restrict__ W1, unsigned short* __restrict__ Wbot1,
                           unsigned short* __restrict__ Wd1,
                           const float* __restrict__ Wc0, unsigned short* __restrict__ Wtb0,
                           const float* __restrict__ Wc1, unsigned short* __restrict__ Wtb1,
                           const int* __restrict__ ei0, const int* __restrict__ ei1,
                           int* __restrict__ cnt0, int* __restrict__ cnt1,
                           int* __restrict__ slot0, int* __restrict__ slot1) {
  int b = blockIdx.x;
  int tid = threadIdx.x;
  if (b < 128) {
    int idx = b * 256 + tid;          // 32768 = 256*128
    int n = idx >> 7, k = idx & 127;
    float top = W0[(size_t)k * 256 + n];
    float bot = W0[(size_t)(128 + k) * 256 + n];
    Wbot0[idx] = f2bf(bot);
    Wd0[idx]   = f2bf(top - bot);
  } else if (b < 384) {
    int idx = (b - 128) * 256 + tid;  // 65536 = 256*256
    int n = idx >> 8, k = idx & 255;
    float top = W1[(size_t)k * 256 + n];
    float bot = W1[(size_t)(256 + k) * 256 + n];
    Wbot1[idx] = f2bf(bot);
    Wd1[idx]   = f2bf(top - bot);
  } else if (b < 1664) {
    int idx = (b - 384) * 256 + tid;  // 5*65536
    int tap = idx >> 16, o = (idx >> 8) & 255, i = idx & 255;
    Wtb0[idx] = f2bf(Wc0[((size_t)o * 256 + i) * 5 + tap]);
  } else if (b < 2944) {
    int idx = (b - 1664) * 256 + tid;
    int tap = idx >> 16, o = (idx >> 8) & 255, i = idx & 255;
    Wtb1[idx] = f2bf(Wc1[((size_t)o * 256 + i) * 5 + tap]);
  } else {
    int e = (b - 2944) * 256 + tid;   // E0+E1 = 393216 over 1536 blocks
    if (e < E0) {
      int d = ei0[E0 + e];
      int p = atomicAdd(&cnt0[d], 1);
      if (p < CAP) slot0[(size_t)d * CAP + p] = ei0[e];
    } else {
      int e2 = e - E0;
      int d = ei1[E1 + e2];
      int p = atomicAdd(&cnt1[d], 1);
      if (p < CAP) slot1[(size_t)d * CAP + p] = ei1[e2];
    }
  }
}

// ---------------- fused dual-output MFMA GEMM ----------------
// One block: 64 rows x 128 cols, computing BOTH Bm = A@Wbot (bf16)
// and P = A@Wd + bias (bf16). A staged once per kb; Wbot/Wd in two LDS buffers.
// F32A: A is the fp32 `data` tensor [T][BN][F]; row bn*T0+t is gathered and
// converted to bf16 during staging (identical rounding to the old permute).
template <bool F32A>
__global__ __launch_bounds__(256) void k_gemm2(const float* __restrict__ Af,
                                               const unsigned short* __restrict__ Ab,
                                               const unsigned short* __restrict__ Wbot,
                                               const unsigned short* __restrict__ Wd,
                                               unsigned short* __restrict__ Bm,
                                               unsigned short* __restrict__ P, int K,
                                               const float* __restrict__ bias) {
  __shared__ __align__(16) short A_lds[64 * 72];
  __shared__ __align__(16) short B0_lds[128 * 72];
  __shared__ __align__(16) short B1_lds[128 * 72];
  int tid = threadIdx.x;
  int row0 = blockIdx.x * 64;
  int col0 = blockIdx.y * 128;
  int lane = tid & 63, wv = tid >> 6;
  int m16 = lane & 15, quad = lane >> 4;
  int sr = tid >> 3, sseg = tid & 7;

  floatx4 accB[8], accP[8];
#pragma unroll
  for (int nt = 0; nt < 8; ++nt) {
    accB[nt] = (floatx4){0.f, 0.f, 0.f, 0.f};
    accP[nt] = (floatx4){0.f, 0.f, 0.f, 0.f};
  }

  for (int kb = 0; kb < K; kb += 64) {
    __syncthreads();
#pragma unroll
    for (int i = 0; i < 2; ++i) {
      int r = sr + i * 32;
      if (F32A) {
        int rg = row0 + r;
        int t = rg & (T0 - 1), bn = rg >> 7;
        const float* s = Af + ((size_t)t * BN + bn) * Ff + kb + sseg * 8;
        float4 f0 = *(const float4*)s;
        float4 f1 = *(const float4*)(s + 4);
        unsigned short o[8];
        o[0] = f2bf(f0.x); o[1] = f2bf(f0.y); o[2] = f2bf(f0.z); o[3] = f2bf(f0.w);
        o[4] = f2bf(f1.x); o[5] = f2bf(f1.y); o[6] = f2bf(f1.z); o[7] = f2bf(f1.w);
        *(int4*)&A_lds[r * 72 + sseg * 8] = *(int4*)o;
      } else {
        *(int4*)&A_lds[r * 72 + sseg * 8] =
            *(const int4*)(Ab + (size_t)(row0 + r) * K + kb + sseg * 8);
      }
    }
#pragma unroll
    for (int i = 0; i < 4; ++i) {
      int r = sr + i * 32;
      *(int4*)&B0_lds[r * 72 + sseg * 8] =
          *(const int4*)(Wbot + (size_t)(col0 + r) * K + kb + sseg * 8);
      *(int4*)&B1_lds[r * 72 + sseg * 8] =
          *(const int4*)(Wd + (size_t)(col0 + r) * K + kb + sseg * 8);
    }
    __syncthreads();
#pragma unroll
    for (int ks = 0; ks < 2; ++ks) {
      bhalf8 a = *(const bhalf8*)&A_lds[(wv * 16 + m16) * 72 + ks * 32 + quad * 8];
#pragma unroll
      for (int nt = 0; nt < 8; ++nt) {
        bhalf8 b0 = *(const bhalf8*)&B0_lds[(nt * 16 + m16) * 72 + ks * 32 + quad * 8];
        accB[nt] = __builtin_amdgcn_mfma_f32_16x16x32_bf16(a, b0, accB[nt], 0, 0, 0);
        bhalf8 b1 = *(const bhalf8*)&B1_lds[(nt * 16 + m16) * 72 + ks * 32 + quad * 8];
        accP[nt] = __builtin_amdgcn_mfma_f32_16x16x32_bf16(a, b1, accP[nt], 0, 0, 0);
      }
    }
  }

  int g0 = row0 + wv * 16 + quad * 4;
#pragma unroll
  for (int nt = 0; nt < 8; ++nt) {
    int c = col0 + nt * 16 + m16;
    float bv = bias[c];
#pragma unroll
    for (int r = 0; r < 4; ++r) {
      Bm[(size_t)(g0 + r) * 256 + c] = f2bf(accB[nt][r]);
      P[(size_t)(g0 + r) * 256 + c]  = f2bf(accP[nt][r] + bv);
    }
  }
}

// ---------------- segment max + fused relu epilogue ----------------
// per node: M = max over in-edge sources of Bm rows (-inf if empty),
// X1 = relu(P + M)  (empty -> relu(-inf) = 0, matching PyG fill).
// Gather issues 8 concurrent predicated row loads per pass (index clamped to
// n-1; duplicate maxes are idempotent) to keep 8 LLC fetches in flight.
__global__ __launch_bounds__(256) void k_maxg2(const unsigned short* __restrict__ Bm,
                                               const int* __restrict__ cnt,
                                               const int* __restrict__ slot,
                                               const unsigned short* __restrict__ P,
                                               unsigned short* __restrict__ X1) {
  int node = blockIdx.x * 4 + (threadIdx.x >> 6);
  int lane = threadIdx.x & 63;
  int n = cnt[node];
  if (n > CAP) n = CAP;
  const int* sl = slot + (size_t)node * CAP;
  float4 m = make_float4(-INFINITY, -INFINITY, -INFINITY, -INFINITY);
  for (int i = 0; i < n; i += 8) {
    int s[8];
#pragma unroll
    for (int j = 0; j < 8; ++j) {
      int idx = i + j;
      s[j] = sl[(idx < n) ? idx : (n - 1)];
    }
    ushort4 v[8];
#pragma unroll
    for (int j = 0; j < 8; ++j)
      v[j] = *(const ushort4*)(Bm + (size_t)s[j] * 256 + lane * 4);
#pragma unroll
    for (int j = 0; j < 8; ++j) {
      m.x = fmaxf(m.x, bf2f(v[j].x));
      m.y = fmaxf(m.y, bf2f(v[j].y));
      m.z = fmaxf(m.z, bf2f(v[j].z));
      m.w = fmaxf(m.w, bf2f(v[j].w));
    }
  }
  ushort4 p = *(const ushort4*)(P + (size_t)node * 256 + lane * 4);
  ushort4 o;
  o.x = f2bf(fmaxf(bf2f(p.x) + m.x, 0.f));
  o.y = f2bf(fmaxf(bf2f(p.y) + m.y, 0.f));
  o.z = f2bf(fmaxf(bf2f(p.z) + m.z, 0.f));
  o.w = f2bf(fmaxf(bf2f(p.w) + m.w, 0.f));
  *(ushort4*)(X1 + (size_t)node * 256 + lane * 4) = o;
}

// ---------------- MFMA temporal conv: 32x32x16, 128-row x 64-col blocks ----------------
// Y = maxpool2(relu(conv1d(X, Wtb, k=5, pad=2) + bc)); X bf16 [M][256] as [BN][TRows][256]
// R10 geometry (best measured): 4 waves, wave w: row half h=(w&1) with its own 68-row
// halo window (2 row-tiles of 32), col half c=(w>>1) (1 col-tile of 32... here 2 waves
// per col half of 32 each -> col0 + cpart*32). Per K-chunk of 32: stage 2 halo windows
// + all 5 taps of B; grid L0=1024 blocks (4/CU at 36.5 KB LDS).
// C/D layout (32x32): col=lane&31, row=(reg&3)+8*(reg>>2)+4*(lane>>5); pool pairs are
// adjacent regs in the same lane.
template <int TRows, bool OUT_F32>
__global__ __launch_bounds__(256) void k_conv32(const unsigned short* __restrict__ X,
                                                const unsigned short* __restrict__ Wtb,
                                                const float* __restrict__ bc,
                                                void* __restrict__ Yout) {
  __shared__ __align__(16) short A_lds[2 * 68 * 40];   // [win][row 0..67][k32 + pad8]
  __shared__ __align__(16) short B_lds[5 * 64 * 40];   // [tap*64 + col][k32 + pad8]
  int tid = threadIdx.x;
  int row0 = blockIdx.x * 128;
  int col0 = blockIdx.y * 64;
  int lane = tid & 63, wv = tid >> 6;
  int l31 = lane & 31, khalf = lane >> 5;
  int h = wv & 1, cpart = wv >> 1;

  floatx16 acc[2];
#pragma unroll
  for (int rt = 0; rt < 2; ++rt)
#pragma unroll
    for (int r = 0; r < 16; ++r) acc[rt][r] = 0.f;

  for (int kb = 0; kb < 256; kb += 32) {
    __syncthreads();
    // stage A: two 68-row halo windows (rows base-2 .. base+66), zero outside bn
    for (int u = tid; u < 544; u += 256) {
      int s = (u >= 272) ? 1 : 0;
      int v = u - s * 272;
      int rr = v >> 2, seg = v & 3;
      int base = row0 + s * 64;
      int lo = base & ~(TRows - 1);
      int gr = base + rr - 2;
      int4 val = {0, 0, 0, 0};
      if (gr >= lo && gr < lo + TRows)
        val = *(const int4*)(X + (size_t)gr * 256 + kb + seg * 8);
      *(int4*)&A_lds[(s * 68 + rr) * 40 + seg * 8] = val;
    }
    // stage B: 5 taps x 64 cols x 32 k
#pragma unroll
    for (int i = 0; i < 5; ++i) {
      int u = tid + i * 256;            // 320 rows x 4 segs
      int r = u >> 2, seg = u & 3;      // r = tap*64 + col
      int tap = r >> 6, col = r & 63;
      *(int4*)&B_lds[r * 40 + seg * 8] =
          *(const int4*)(Wtb + (size_t)tap * 65536 + (size_t)(col0 + col) * 256 + kb + seg * 8);
    }
    __syncthreads();
#pragma unroll
    for (int tap = 0; tap < 5; ++tap) {
#pragma unroll
      for (int ks = 0; ks < 2; ++ks) {
        int ko = ks * 16 + khalf * 8;
        bhalf8 a0 = *(const bhalf8*)&A_lds[(h * 68 + l31 + tap) * 40 + ko];
        bhalf8 a1 = *(const bhalf8*)&A_lds[(h * 68 + 32 + l31 + tap) * 40 + ko];
        bhalf8 b = *(const bhalf8*)&B_lds[((tap << 6) + cpart * 32 + l31) * 40 + ko];
        acc[0] = __builtin_amdgcn_mfma_f32_32x32x16_bf16(a0, b, acc[0], 0, 0, 0);
        acc[1] = __builtin_amdgcn_mfma_f32_32x32x16_bf16(a1, b, acc[1], 0, 0, 0);
      }
    }
  }

#pragma unroll
  for (int rt = 0; rt < 2; ++rt) {
    int c = col0 + cpart * 32 + l31;
    float bv = bc[c];
#pragma unroll
    for (int r = 0; r < 16; r += 2) {
      int rowg = row0 + h * 64 + rt * 32 + 4 * khalf + 8 * (r >> 2) + (r & 3);
      float y0 = fmaxf(acc[rt][r] + bv, 0.f);
      float y1 = fmaxf(acc[rt][r + 1] + bv, 0.f);
      float p = fmaxf(y0, y1);
      int o = rowg >> 1;
      if (OUT_F32) ((float*)Yout)[(size_t)o * 256 + c] = p;
      else ((unsigned short*)Yout)[(size_t)o * 256 + c] = f2bf(p);
    }
  }
}

extern "C" void kernel_launch(void* const* d_in, const int* in_sizes, int n_in,
                              void* d_out, int out_size, void* d_ws, size_t ws_size,
                              hipStream_t stream) {
  const float* data = (const float*)d_in[0];
  const int* ei0 = (const int*)d_in[2];
  const int* ei1 = (const int*)d_in[3];
  const float* W0  = (const float*)d_in[4];
  const float* b0  = (const float*)d_in[5];
  const float* Wc0 = (const float*)d_in[6];
  const float* bc0 = (const float*)d_in[7];
  const float* W1  = (const float*)d_in[8];
  const float* b1  = (const float*)d_in[9];
  const float* Wc1 = (const float*)d_in[10];
  const float* bc1 = (const float*)d_in[11];
  float* out = (float*)d_out;

  char* base = (char*)d_ws;
  size_t off = 0;
  auto alloc = [&](size_t bytes) { void* p = base + off; off += (bytes + 255) & ~(size_t)255; return p; };
  unsigned short* Bm    = (unsigned short*)alloc((size_t)NODE0 * Hh * 2);
  unsigned short* P     = (unsigned short*)alloc((size_t)NODE0 * Hh * 2);
  unsigned short* X1b   = (unsigned short*)alloc((size_t)NODE0 * Hh * 2);
  unsigned short* Y0b   = (unsigned short*)alloc((size_t)NODE1 * Hh * 2);
  unsigned short* Wbot0 = (unsigned short*)alloc(256 * 128 * 2);
  unsigned short* Wd0   = (unsigned short*)alloc(256 * 128 * 2);
  unsigned short* Wbot1 = (unsigned short*)alloc(256 * 256 * 2);
  unsigned short* Wd1   = (unsigned short*)alloc(256 * 256 * 2);
  unsigned short* Wtb0  = (unsigned short*)alloc(5 * 65536 * 2);
  unsigned short* Wtb1  = (unsigned short*)alloc(5 * 65536 * 2);
  int* cnt0  = (int*)alloc(NODE0 * 4);      // cnt0+cnt1 adjacent: one memset
  int* cnt1  = (int*)alloc(NODE1 * 4);
  int* slot0 = (int*)alloc((size_t)NODE0 * CAP * 4);
  int* slot1 = (int*)alloc((size_t)NODE1 * CAP * 4);

  hipMemsetAsync(cnt0, 0, (NODE0 + NODE1) * sizeof(int), stream);

  k_prepfill<<<4480, 256, 0, stream>>>(W0, Wbot0, Wd0, W1, Wbot1, Wd1,
                                       Wc0, Wtb0, Wc1, Wtb1,
                                       ei0, ei1, cnt0, cnt1, slot0, slot1);

  // ---- layer 0 ----
  k_gemm2<true><<<dim3(NODE0 / 64, 2), 256, 0, stream>>>(data, nullptr, Wbot0, Wd0, Bm, P, 128, b0);
  k_maxg2<<<NODE0 / 4, 256, 0, stream>>>(Bm, cnt0, slot0, P, X1b);
  k_conv32<128, false><<<dim3(NODE0 / 128, 4), 256, 0, stream>>>(X1b, Wtb0, bc0, Y0b);

  // ---- layer 1 ----
  k_gemm2<false><<<dim3(NODE1 / 64, 2), 256, 0, stream>>>(nullptr, Y0b, Wbot1, Wd1, Bm, P, 256, b1);
  k_maxg2<<<NODE1 / 4, 256, 0, stream>>>(Bm, cnt1, slot1, P, X1b);
  k_conv32<64, true><<<dim3(NODE1 / 128, 4), 256, 0, stream>>>(X1b, Wtb1, bc1, out);
}